// Round 4
// baseline (389.401 us; speedup 1.0000x reference)
//
#include <hip/hip_runtime.h>
#include <math.h>

// VolumeCarver: out[r] = sum_i alpha_i * prod_{j=1..i} trans_j  (includes j=i, excludes j=0)
// alpha_i = 1 - exp(-sigmoid(logits[leaf_i]) * delta_i); trans_j = min(1, 1-alpha_j+1e-10).
//
// R9: single-kernel version. vc_kernel is pinned at the divergent-gather roofline
// (~3 cy per random lane-request/CU; R5 baseline, R6 2x-MLP pipeline, R7 L1-bypass
// all land 164-168us). The fp16 table pre-pass buys nothing on the gather path
// (one aligned-dword request per sample either way), so gather the raw f32 logit
// and apply sigmoid inline: removes the sig_kernel dispatch + its stream
// dependency bubble. VALU has 86% headroom for the inline sigmoid.

#define NRAYS 262144
#define LEN   128
#define NLEAF 1048576
#define MAXD  1e10f
#define EPSW  1e-10f

typedef float v4f __attribute__((ext_vector_type(4)));
typedef int   v4i __attribute__((ext_vector_type(4)));

__device__ __forceinline__ float fast_sigmoid(float x) {
    return __builtin_amdgcn_rcpf(1.0f + __expf(-x));
}

// 1 - exp(-x), x >= 0. Poly for small x (rel err < 2e-7 for x < 0.1).
__device__ __forceinline__ float omexp(float x) {
    float p = x * (1.0f + x * (-0.5f + x * (0.16666667f - 0.041666668f * x)));
    return (x < 0.1f) ? p : (1.0f - __expf(-x));
}

__global__ __launch_bounds__(256) void vc_kernel(
    const float* __restrict__ t_stops,   // [R, L]
    const int*   __restrict__ leaves,    // [R, L]
    const float* __restrict__ logits,    // [NLEAF] raw f32 logits
    float*       __restrict__ out)       // [R]
{
    const int lane = threadIdx.x & 63;
    const int wid  = blockIdx.x * 4 + (threadIdx.x >> 6);
    const int ray  = wid * 8 + (lane >> 3);          // 8 rays per wave
    const int sub  = lane & 7;                       // 8 lanes per ray
    const int gbase = lane & 56;                     // first lane of this ray group

    // chunk c covers elements [c*32 + sub*4 .. +3] of the ray (c = 0..3)
    const long long rb = (long long)ray * LEN + sub * 4;

    v4i lv[4];
    v4f tt[4];
    #pragma unroll
    for (int c = 0; c < 4; ++c)
        lv[c] = __builtin_nontemporal_load((const v4i*)(leaves + rb + c * 32));
    #pragma unroll
    for (int c = 0; c < 4; ++c)
        tt[c] = __builtin_nontemporal_load((const v4f*)(t_stops + rb + c * 32));

    // 16 independent gathers issued back-to-back (cached loads: table has
    // ~32x reuse per entry and lives in L2/L3).
    float lg[4][4];
    #pragma unroll
    for (int c = 0; c < 4; ++c) {
        lg[c][0] = logits[lv[c].x];
        lg[c][1] = logits[lv[c].y];
        lg[c][2] = logits[lv[c].z];
        lg[c][3] = logits[lv[c].w];
    }

    float op[4][4];
    #pragma unroll
    for (int c = 0; c < 4; ++c) {
        op[c][0] = fast_sigmoid(lg[c][0]);
        op[c][1] = fast_sigmoid(lg[c][1]);
        op[c][2] = fast_sigmoid(lg[c][2]);
        op[c][3] = fast_sigmoid(lg[c][3]);
    }

    // Per-chunk local (P,S) over the lane's 4 consecutive elements.
    float P[4], S[4];
    #pragma unroll
    for (int c = 0; c < 4; ++c) {
        // value of the element AFTER this lane's last one in chunk c:
        //   sub<7 : next lane's tt[c].x
        //   sub==7: chunk c+1's tt.x at group's lane 0 (or MAXD at ray end)
        float nxt_dn = __shfl_down(tt[c].x, 1);
        float nxt_c1 = (c < 3) ? __shfl(tt[(c + 1) & 3].x, gbase) : MAXD;
        float nxt = (sub == 7) ? nxt_c1 : nxt_dn;

        float d0 = tt[c].y - tt[c].x;
        float d1 = tt[c].z - tt[c].y;
        float d2 = tt[c].w - tt[c].z;
        float d3 = nxt - tt[c].w;

        float a0 = omexp(op[c][0] * d0);
        float a1 = omexp(op[c][1] * d1);
        float a2 = omexp(op[c][2] * d2);
        float a3 = omexp(op[c][3] * d3);

        float r0 = fminf(1.0f, 1.0f - a0 + EPSW);
        float r1 = fminf(1.0f, 1.0f - a1 + EPSW);
        float r2 = fminf(1.0f, 1.0f - a2 + EPSW);
        float r3 = fminf(1.0f, 1.0f - a3 + EPSW);
        if (c == 0 && sub == 0) r0 = 1.0f;   // ray's trans[0] excluded everywhere

        float cc = r0;        float ss = a0 * cc;
        cc *= r1;             ss = fmaf(a1, cc, ss);
        cc *= r2;             ss = fmaf(a2, cc, ss);
        cc *= r3;             ss = fmaf(a3, cc, ss);
        P[c] = cc;  S[c] = ss;
    }

    // Ordered butterfly over the 8-lane ray group, all 4 chunks concurrently.
    #pragma unroll
    for (int o = 1; o < 8; o <<= 1) {
        #pragma unroll
        for (int c = 0; c < 4; ++c) {
            float Pp = __shfl_xor(P[c], o);
            float Sp = __shfl_xor(S[c], o);
            S[c] = (lane & o) ? fmaf(Pp, S[c], Sp) : fmaf(P[c], Sp, S[c]);
            P[c] *= Pp;
        }
    }

    // Chain the 4 chunk segments in order.
    float Sr = fmaf(P[2], S[3], S[2]);
    Sr = fmaf(P[1], Sr, S[1]);
    Sr = fmaf(P[0], Sr, S[0]);

    if (sub == 0)
        out[ray] = Sr;
}

extern "C" void kernel_launch(void* const* d_in, const int* in_sizes, int n_in,
                              void* d_out, int out_size, void* d_ws, size_t ws_size,
                              hipStream_t stream) {
    const float* t_stops = (const float*)d_in[0];
    const int*   leaves  = (const int*)d_in[1];
    const float* logits  = (const float*)d_in[2];
    float*       out     = (float*)d_out;

    // 32 rays per 256-thread block (8 rays per wave), single dispatch.
    vc_kernel<<<NRAYS / 32, 256, 0, stream>>>(t_stops, leaves, logits, out);
}

// Round 5
// 367.163 us; speedup vs baseline: 1.0606x; 1.0606x over previous
//
#include <hip/hip_runtime.h>
#include <hip/hip_fp16.h>
#include <math.h>

// VolumeCarver: out[r] = sum_i alpha_i * prod_{j=1..i} trans_j  (includes j=i, excludes j=0)
// alpha_i = 1 - exp(-sigmoid(logits[leaf_i]) * delta_i); trans_j = min(1, 1-alpha_j+1e-10).
//
// R10 = R8 revert (best verified config). Ledger:
//   R5 (this structure)                 163-166 us vc, ~366 us total
//   R6 (persistent 2x-MLP pipeline)     flat      -> not MLP-limited
//   R7 (sc0 L1-bypass gathers)          flat      -> not MSHR/fill-limited
//   R9 (no table, f32 gather)           +24 us, FETCH +103 MB -> 4 MB table
//       thrashes L2 (table must stay 2 MB to co-reside with stream traffic)
// Conclusion: vc_kernel is pinned at ~3 cy per divergent lane-request per CU
// (TA/TCP address-serialization roofline); fp16 table keeps fills in L2.

#define NRAYS 262144
#define LEN   128
#define NLEAF 1048576
#define MAXD  1e10f
#define EPSW  1e-10f

typedef float v4f __attribute__((ext_vector_type(4)));
typedef int   v4i __attribute__((ext_vector_type(4)));
typedef short v8s __attribute__((ext_vector_type(8)));

__device__ __forceinline__ float fast_sigmoid(float x) {
    return __builtin_amdgcn_rcpf(1.0f + __expf(-x));
}

// 1 - exp(-x), x >= 0. Poly for small x (rel err < 2e-7 for x < 0.1).
__device__ __forceinline__ float omexp(float x) {
    float p = x * (1.0f + x * (-0.5f + x * (0.16666667f - 0.041666668f * x)));
    return (x < 0.1f) ? p : (1.0f - __expf(-x));
}

// Dword-aligned gather of fp16 entry idx from table (2B entries packed in dwords).
__device__ __forceinline__ float tab_gather32(const unsigned int* tb32, int idx) {
    unsigned int v = tb32[idx >> 1];
    unsigned short u = (unsigned short)(v >> ((idx & 1) * 16));
    __half h;
    *(unsigned short*)&h = u;
    return __half2float(h);
}

__device__ __forceinline__ short half_bits(float x) {
    __half h = __float2half(x);
    return *(short*)&h;
}

// 8 elements per thread: 2x float4 load, 1x 16B store. grid = NLEAF/2048 = 512.
__global__ __launch_bounds__(256) void sig_kernel(const float* __restrict__ logits,
                                                  __half* __restrict__ tab) {
    int i = (blockIdx.x * 256 + threadIdx.x) * 8;
    v4f a = *(const v4f*)(logits + i);
    v4f b = *(const v4f*)(logits + i + 4);
    v8s r;
    r[0] = half_bits(fast_sigmoid(a.x));
    r[1] = half_bits(fast_sigmoid(a.y));
    r[2] = half_bits(fast_sigmoid(a.z));
    r[3] = half_bits(fast_sigmoid(a.w));
    r[4] = half_bits(fast_sigmoid(b.x));
    r[5] = half_bits(fast_sigmoid(b.y));
    r[6] = half_bits(fast_sigmoid(b.z));
    r[7] = half_bits(fast_sigmoid(b.w));
    *(v8s*)((short*)tab + i) = r;
}

template <bool TAB>
__global__ __launch_bounds__(256) void vc_kernel(
    const float* __restrict__ t_stops,   // [R, L]
    const int*   __restrict__ leaves,    // [R, L]
    const void*  __restrict__ table,     // fp16 sigmoid table (TAB) or raw f32 logits
    float*       __restrict__ out)       // [R]
{
    const int lane = threadIdx.x & 63;
    const int wid  = blockIdx.x * 4 + (threadIdx.x >> 6);
    const int ray  = wid * 8 + (lane >> 3);          // 8 rays per wave
    const int sub  = lane & 7;                       // 8 lanes per ray
    const int gbase = lane & 56;                     // first lane of this ray group

    // chunk c covers elements [c*32 + sub*4 .. +3] of the ray (c = 0..3)
    const long long rb = (long long)ray * LEN + sub * 4;

    v4i lv[4];
    v4f tt[4];
    #pragma unroll
    for (int c = 0; c < 4; ++c)
        lv[c] = __builtin_nontemporal_load((const v4i*)(leaves + rb + c * 32));
    #pragma unroll
    for (int c = 0; c < 4; ++c)
        tt[c] = __builtin_nontemporal_load((const v4f*)(t_stops + rb + c * 32));

    // 16 independent gathers issued back-to-back.
    float op[4][4];
    if (TAB) {
        const unsigned int* tb32 = (const unsigned int*)table;
        #pragma unroll
        for (int c = 0; c < 4; ++c) {
            op[c][0] = tab_gather32(tb32, lv[c].x);
            op[c][1] = tab_gather32(tb32, lv[c].y);
            op[c][2] = tab_gather32(tb32, lv[c].z);
            op[c][3] = tab_gather32(tb32, lv[c].w);
        }
    } else {
        const float* lg = (const float*)table;
        #pragma unroll
        for (int c = 0; c < 4; ++c) {
            op[c][0] = fast_sigmoid(lg[lv[c].x]);
            op[c][1] = fast_sigmoid(lg[lv[c].y]);
            op[c][2] = fast_sigmoid(lg[lv[c].z]);
            op[c][3] = fast_sigmoid(lg[lv[c].w]);
        }
    }

    // Per-chunk local (P,S) over the lane's 4 consecutive elements.
    float P[4], S[4];
    #pragma unroll
    for (int c = 0; c < 4; ++c) {
        // value of the element AFTER this lane's last one in chunk c:
        //   sub<7 : next lane's tt[c].x
        //   sub==7: chunk c+1's tt.x at group's lane 0 (or MAXD at ray end)
        float nxt_dn = __shfl_down(tt[c].x, 1);
        float nxt_c1 = (c < 3) ? __shfl(tt[(c + 1) & 3].x, gbase) : MAXD;
        float nxt = (sub == 7) ? nxt_c1 : nxt_dn;

        float d0 = tt[c].y - tt[c].x;
        float d1 = tt[c].z - tt[c].y;
        float d2 = tt[c].w - tt[c].z;
        float d3 = nxt - tt[c].w;

        float a0 = omexp(op[c][0] * d0);
        float a1 = omexp(op[c][1] * d1);
        float a2 = omexp(op[c][2] * d2);
        float a3 = omexp(op[c][3] * d3);

        float r0 = fminf(1.0f, 1.0f - a0 + EPSW);
        float r1 = fminf(1.0f, 1.0f - a1 + EPSW);
        float r2 = fminf(1.0f, 1.0f - a2 + EPSW);
        float r3 = fminf(1.0f, 1.0f - a3 + EPSW);
        if (c == 0 && sub == 0) r0 = 1.0f;   // ray's trans[0] excluded everywhere

        float cc = r0;        float ss = a0 * cc;
        cc *= r1;             ss = fmaf(a1, cc, ss);
        cc *= r2;             ss = fmaf(a2, cc, ss);
        cc *= r3;             ss = fmaf(a3, cc, ss);
        P[c] = cc;  S[c] = ss;
    }

    // Ordered butterfly over the 8-lane ray group, all 4 chunks concurrently.
    #pragma unroll
    for (int o = 1; o < 8; o <<= 1) {
        #pragma unroll
        for (int c = 0; c < 4; ++c) {
            float Pp = __shfl_xor(P[c], o);
            float Sp = __shfl_xor(S[c], o);
            S[c] = (lane & o) ? fmaf(Pp, S[c], Sp) : fmaf(P[c], Sp, S[c]);
            P[c] *= Pp;
        }
    }

    // Chain the 4 chunk segments in order.
    float Sr = fmaf(P[2], S[3], S[2]);
    Sr = fmaf(P[1], Sr, S[1]);
    Sr = fmaf(P[0], Sr, S[0]);

    if (sub == 0)
        out[ray] = Sr;
}

extern "C" void kernel_launch(void* const* d_in, const int* in_sizes, int n_in,
                              void* d_out, int out_size, void* d_ws, size_t ws_size,
                              hipStream_t stream) {
    const float* t_stops = (const float*)d_in[0];
    const int*   leaves  = (const int*)d_in[1];
    const float* logits  = (const float*)d_in[2];
    float*       out     = (float*)d_out;

    if (ws_size >= NLEAF * sizeof(__half)) {
        sig_kernel<<<NLEAF / 2048, 256, 0, stream>>>(logits, (__half*)d_ws);
        // 32 rays per 256-thread block (8 rays per wave)
        vc_kernel<true><<<NRAYS / 32, 256, 0, stream>>>(t_stops, leaves, d_ws, out);
    } else {
        vc_kernel<false><<<NRAYS / 32, 256, 0, stream>>>(t_stops, leaves, logits, out);
    }
}